// Round 10
// baseline (442.156 us; speedup 1.0000x reference)
//
#include <hip/hip_runtime.h>

#define NN 100000   // nodes
#define NE 1600000  // edges
#define FD 128      // feature dim (4 heads x 32 ch); fp8 row = 128 B
#define NB 391      // ceil(NN/256) dst-buckets
#define CAP 4800    // padded bucket capacity (mean 4096, sigma 64 -> +11 sigma)
#define CHUNK 8192  // edges per k_bucket block -> 196 blocks
#define GB 782      // gemm tiles (128 rows each)
#define AB 25000    // agg blocks (4 nodes each, 1 node per wave)
#define PBLK2 512   // second-stage pool rows

typedef __attribute__((ext_vector_type(8))) short bf16x8;
typedef __attribute__((ext_vector_type(4))) float f32x4;
typedef __attribute__((ext_vector_type(2))) float f32x2;

union B8 { bf16x8 v; unsigned int u[4]; };

// ---------------- helpers ----------------

__device__ __forceinline__ unsigned short f2bf(float x) {
    unsigned int u = __float_as_uint(x);
    u += 0x7fffu + ((u >> 16) & 1u);   // round-to-nearest-even
    return (unsigned short)(u >> 16);
}

__device__ __forceinline__ unsigned char f2fp8(float x) {
    // low byte of packed fp8 conversion (RNE, saturating)
    return (unsigned char)__builtin_amdgcn_cvt_pk_fp8_f32(x, 0.f, 0u, false);
}

__device__ __forceinline__ unsigned int pkhi(unsigned int ua, unsigned int ub) {
    return __builtin_amdgcn_perm(ub, ua, 0x07060302);
}

// pack 8 f32 -> 8 bf16 (hi 16 bits, truncation — same grid as all passing rounds)
__device__ __forceinline__ bf16x8 pack8hi(const float4& x0, const float4& x1) {
    float f[8] = {x0.x, x0.y, x0.z, x0.w, x1.x, x1.y, x1.z, x1.w};
    B8 H;
#pragma unroll
    for (int i = 0; i < 4; i++) {
        unsigned int ua = __float_as_uint(f[2 * i]);
        unsigned int ub = __float_as_uint(f[2 * i + 1]);
        H.u[i] = pkhi(ua, ub);
    }
    return H.v;
}

// ---------------- W -> bf16 + gcur zeroing (one dispatch) ----------------

__global__ void k_wsplit(const float* __restrict__ W1, const float* __restrict__ W2,
                         const float* __restrict__ W3, unsigned short* __restrict__ Wth,
                         int* __restrict__ gcur) {
    int gid = blockIdx.x * 256 + threadIdx.x;  // 0..49151
    if (gid < NB) gcur[gid] = 0;
    int w = gid >> 14;
    int tid = gid & 16383;
    const float* W = (w == 0) ? W1 : (w == 1) ? W2 : W3;
    int n = tid >> 7, k = tid & 127;
    Wth[gid] = f2bf(W[k * 128 + n]);   // RNE bf16 weights
}

// ---------------- bucket scatter into padded per-bucket slots ----------------
// pairs[b*CAP + slot] = src | (dst&255)<<17

__global__ __launch_bounds__(256) void k_bucket(const int* __restrict__ src,
                                                const int* __restrict__ dst,
                                                int* __restrict__ gcur,
                                                unsigned int* __restrict__ pairs) {
    __shared__ int scnt[NB];
    __shared__ int sbase[NB];
    int t = threadIdx.x;
    for (int i = t; i < NB; i += 256) scnt[i] = 0;
    __syncthreads();
    int e0 = blockIdx.x * CHUNK, e1 = min(e0 + CHUNK, NE);
    for (int i = e0 + t; i < e1; i += 256) atomicAdd(&scnt[dst[i] >> 8], 1);
    __syncthreads();
    for (int i = t; i < NB; i += 256) {
        int c = scnt[i];
        sbase[i] = (c > 0) ? (i * CAP + atomicAdd(&gcur[i], c)) : 0;
        scnt[i] = 0;  // reuse as local cursor
    }
    __syncthreads();
    for (int i = e0 + t; i < e1; i += 256) {
        int d = dst[i];
        int b = d >> 8;
        int r = atomicAdd(&scnt[b], 1);
        pairs[sbase[b] + r] = (unsigned int)src[i] | ((unsigned int)(d & 255) << 17);
    }
}

// ---------------- per-bucket counting sort body ----------------

__device__ void bsort_body(int b, const unsigned int* __restrict__ pairs,
                           const int* __restrict__ gcur, int* __restrict__ off,
                           int* __restrict__ deg, int* __restrict__ ssrc) {
    __shared__ int hcnt[256];
    __shared__ int cur[256];
    int t = threadIdx.x;
    int cnt = gcur[b];
    int estart = b * CAP;
    hcnt[t] = 0;
    __syncthreads();
    for (int i = t; i < cnt; i += 256)
        atomicAdd(&hcnt[(pairs[estart + i] >> 17) & 255], 1);
    __syncthreads();
    int v = hcnt[t];
    cur[t] = v;
    __syncthreads();
    for (int o = 1; o < 256; o <<= 1) {
        int x = (t >= o) ? cur[t - o] : 0;
        __syncthreads();
        cur[t] += x;
        __syncthreads();
    }
    int excl = cur[t] - v;
    int node = (b << 8) + t;
    if (node < NN) {
        off[node] = estart + excl;
        deg[node] = v;
    }
    __syncthreads();
    cur[t] = estart + excl;
    __syncthreads();
    for (int i = t; i < cnt; i += 256) {
        unsigned int p = pairs[estart + i];
        int pos = atomicAdd(&cur[(p >> 17) & 255], 1);
        ssrc[pos] = (int)(p & 0x1ffffu);
    }
}

// ---------------- fused GEMM epilogue (2 row-groups): fp8 features + el/er ----------------
// Features staged as fp8 bytes in wave-private LDS, then copied out as uint4
// (coalesced) — avoids 1-byte scattered global stores (partial-line RMW).

__device__ __forceinline__ void epilogue(f32x4 acc[2][8], int row0, int q, int r, int nrows,
                                         const float* __restrict__ al,
                                         const float* __restrict__ ar,
                                         unsigned char* __restrict__ FbG,
                                         float* __restrict__ el, float* __restrict__ er,
                                         unsigned char* __restrict__ sg8, int lane) {
#pragma unroll
    for (int g = 0; g < 2; g++) {
#pragma unroll
        for (int i = 0; i < 4; i++) {
            int row_l = g * 16 + q * 4 + i;
            int row = row0 + row_l;
            float elp[4], erp[4];
#pragma unroll
            for (int h = 0; h < 4; h++) { elp[h] = 0.f; erp[h] = 0.f; }
#pragma unroll
            for (int nt = 0; nt < 8; nt++) {
                int h = nt >> 1;
                int c = ((nt & 1) << 4) + r;
                float v = acc[g][nt][i];
                elp[h] = fmaf(v, al[h * 32 + c], elp[h]);
                erp[h] = fmaf(v, ar[h * 32 + c], erp[h]);
            }
#pragma unroll
            for (int o = 1; o < 16; o <<= 1) {
#pragma unroll
                for (int h = 0; h < 4; h++) {
                    elp[h] += __shfl_xor(elp[h], o);
                    erp[h] += __shfl_xor(erp[h], o);
                }
            }
#pragma unroll
            for (int nt = 0; nt < 8; nt++)
                sg8[row_l * 128 + nt * 16 + r] = f2fp8(acc[g][nt][i]);
            if (row < nrows) {
                int hh = r & 3;
                float ve = (hh & 2) ? ((hh & 1) ? elp[3] : elp[2]) : ((hh & 1) ? elp[1] : elp[0]);
                float vr = (hh & 2) ? ((hh & 1) ? erp[3] : erp[2]) : ((hh & 1) ? erp[1] : erp[0]);
                if (r < 4) el[row * 4 + hh] = ve;
                else if (r < 8) er[row * 4 + hh] = vr;
            }
        }
    }
    // copy out the wave's 32 rows (4 KB), wave-private -> no barrier needed
#pragma unroll
    for (int it = 0; it < 4; it++) {
        int off = it * 1024 + lane * 16;
        int row = row0 + (off >> 7);
        uint4 v = *(const uint4*)(sg8 + off);
        if (row < nrows) *(uint4*)(FbG + (size_t)row * FD + (off & 127)) = v;
    }
}

// ---------------- GEMM body (layer 1): A f32 -> bf16, single MFMA per tile ----------------

__device__ void gemm_f32_body(int bid, const float* __restrict__ A,
                              const unsigned short* __restrict__ Wth,
                              unsigned char* __restrict__ Fb, int nrows,
                              const float* __restrict__ al, const float* __restrict__ ar,
                              float* __restrict__ el, float* __restrict__ er) {
    __shared__ unsigned char sg8[4][4096];   // per-wave fp8 staging (32 rows x 128 B)
    int t = threadIdx.x;
    int wave = t >> 6, lane = t & 63;
    int r = lane & 15, q = lane >> 4;
    int row0 = bid * 128 + wave * 32;
    int rg0 = row0 + r, rg1 = row0 + 16 + r;

    f32x4 acc[2][8];
#pragma unroll
    for (int g = 0; g < 2; g++)
#pragma unroll
        for (int nt = 0; nt < 8; nt++) acc[g][nt] = (f32x4){0.f, 0.f, 0.f, 0.f};

#pragma unroll
    for (int ks = 0; ks < 4; ks++) {
        int k0 = ks * 32 + q * 8;
        float4 z = make_float4(0.f, 0.f, 0.f, 0.f);
        float4 a0 = z, a1 = z, b0 = z, b1 = z;
        if (rg0 < nrows) {
            const float* pa = A + (size_t)rg0 * FD + k0;
            a0 = *(const float4*)pa;
            a1 = *(const float4*)(pa + 4);
        }
        if (rg1 < nrows) {
            const float* pb = A + (size_t)rg1 * FD + k0;
            b0 = *(const float4*)pb;
            b1 = *(const float4*)(pb + 4);
        }
        bf16x8 ah0 = pack8hi(a0, a1);
        bf16x8 ah1 = pack8hi(b0, b1);
#pragma unroll
        for (int nt = 0; nt < 8; nt++) {
            int wo = ((nt * 16 + r) << 7) + k0;
            bf16x8 bh = *(const bf16x8*)(Wth + wo);
            acc[0][nt] = __builtin_amdgcn_mfma_f32_16x16x32_bf16(ah0, bh, acc[0][nt], 0, 0, 0);
            acc[1][nt] = __builtin_amdgcn_mfma_f32_16x16x32_bf16(ah1, bh, acc[1][nt], 0, 0, 0);
        }
    }
    epilogue(acc, row0, q, r, nrows, al, ar, Fb, el, er, sg8[wave], lane);
}

// ---------------- fused dispatch: bsort (blocks 0..NB-1) + layer-1 GEMM (rest) ----------------

__global__ __launch_bounds__(256) void k_sortgemm1(const unsigned int* __restrict__ pairs,
                                                   const int* __restrict__ gcur,
                                                   int* __restrict__ off, int* __restrict__ deg,
                                                   int* __restrict__ ssrc,
                                                   const float* __restrict__ A,
                                                   const unsigned short* __restrict__ Wth,
                                                   unsigned char* __restrict__ Fb,
                                                   const float* __restrict__ al,
                                                   const float* __restrict__ ar,
                                                   float* __restrict__ el,
                                                   float* __restrict__ er) {
    int b = blockIdx.x;
    if (b < NB) bsort_body(b, pairs, gcur, off, deg, ssrc);
    else gemm_f32_body(b - NB, A, Wth, Fb, NN, al, ar, el, er);
}

// ---------------- wave-wide aggregation of one dst node (relu'd output) ----------------
// Features gathered as fp8 (8 B/lane), dequant via v_cvt_pk_f32_fp8, accumulated
// as f32x2 pairs (v_pk_fma_f32 path). Batch loop software-pipelined. The 4-step
// row-group loop early-exits on the WAVE-UNIFORM bound 4k < dg-base: rows beyond
// deg have alpha = 0 (exact no-ops), so skipping them is bit-identical and trims
// ~30% of the cvt/fma/shuffle work at mean degree 16.
// Result: acc8[z] = relu(H[d][8*(lane&15)+z]), replicated across 4 lane-groups.

__device__ __forceinline__ void agg_node(int d,
        const unsigned char* __restrict__ Fb,
        const float* __restrict__ el, const float* __restrict__ er,
        const int* __restrict__ off, const int* __restrict__ deg_,
        const int* __restrict__ ssrc, int lane, float acc8[8]) {
    f32x2 acc2[4];
#pragma unroll
    for (int z = 0; z < 4; z++) acc2[z] = (f32x2){0.f, 0.f};
    int start = off[d];
    int dg = deg_[d];
    if (dg > 0) {
        int h = lane & 3;
        int eloc = lane >> 2;
        int g = lane >> 4;
        int c16 = lane & 15;
        int hsel2 = c16 >> 2;
        float er_h = er[d * 4 + h];
        float s = 0.f;
        // prefetch batch 0's edge data
        bool valid = (eloc < dg);
        int sid = valid ? ssrc[start + eloc] : 0;
        float elv = el[sid * 4 + h];        // sid=0 fallback: valid row, a=0 below
        for (int base = 0; base < dg; base += 16) {
            // alpha for the current batch (inputs prefetched last iteration)
            float v = elv + er_h;
            float e = fmaxf(v, 0.2f * v);   // leaky_relu, exact
            float a = valid ? __expf(e) : 0.f;
            int sidc = sid;
            // prefetch next batch's edge data (latency hides under FMA block)
            int i2 = base + 16 + eloc;
            valid = (i2 < dg);
            sid = valid ? ssrc[start + i2] : 0;
            elv = el[sid * 4 + h];
            s += a;
            int rem = dg - base;            // wave-uniform residual edge count
            // broadcast sids/alphas; issue loads; skip all-zero row groups
#pragma unroll 4
            for (int k = 0; k < 4; k++) {
                if (4 * k >= rem) break;    // uniform branch: rows 4k.. have a=0
                int sl = 16 * k + 4 * g;               // lane holding sid of row 4k+g
                int sv = __shfl(sidc, sl, 64);
                float avk = __shfl(a, sl + hsel2, 64); // alpha for my head
                uint2 u = *(const uint2*)(Fb + (size_t)sv * FD + c16 * 8);
                f32x2 av2 = {avk, avk};
                f32x2 p0 = __builtin_amdgcn_cvt_pk_f32_fp8(u.x, false);
                f32x2 p1 = __builtin_amdgcn_cvt_pk_f32_fp8(u.x, true);
                f32x2 p2 = __builtin_amdgcn_cvt_pk_f32_fp8(u.y, false);
                f32x2 p3 = __builtin_amdgcn_cvt_pk_f32_fp8(u.y, true);
                acc2[0] = __builtin_elementwise_fma(p0, av2, acc2[0]);
                acc2[1] = __builtin_elementwise_fma(p1, av2, acc2[1]);
                acc2[2] = __builtin_elementwise_fma(p2, av2, acc2[2]);
                acc2[3] = __builtin_elementwise_fma(p3, av2, acc2[3]);
            }
        }
        float* accf = (float*)acc2;
        // merge the 4 row-groups (results become replicated wave-wide)
#pragma unroll
        for (int z = 0; z < 8; z++) {
            accf[z] += __shfl_xor(accf[z], 16, 64);
            accf[z] += __shfl_xor(accf[z], 32, 64);
        }
        for (int o = 4; o < 64; o <<= 1) s += __shfl_xor(s, o, 64);
        float inv = 1.f / __shfl(s, hsel2, 64);
#pragma unroll
        for (int z = 0; z < 8; z++) accf[z] *= inv;
    }
    float* accf = (float*)acc2;
#pragma unroll
    for (int z = 0; z < 8; z++) acc8[z] = fmaxf(accf[z], 0.f);   // relu (all 3 layers)
}

// ---------------- standalone agg: 4 waves/block, 1 node/wave, bf16 Hb out ----------------

__global__ __launch_bounds__(256) void k_agg8(
        const unsigned char* __restrict__ Fb,
        const float* __restrict__ el, const float* __restrict__ er,
        const int* __restrict__ off, const int* __restrict__ deg_,
        const int* __restrict__ ssrc,
        unsigned int* __restrict__ Hb) {
    int wave = threadIdx.x >> 6, lane = threadIdx.x & 63;
    int d = blockIdx.x * 4 + wave;
    if (d >= NN) return;
    float acc8[8];
    agg_node(d, Fb, el, er, off, deg_, ssrc, lane, acc8);
    int c16 = lane & 15, g = lane >> 4;
    if (g == 0) {   // 16 lanes write the packed bf16 row (256 B contiguous)
        uint4 pk;
        pk.x = ((unsigned int)f2bf(acc8[1]) << 16) | f2bf(acc8[0]);
        pk.y = ((unsigned int)f2bf(acc8[3]) << 16) | f2bf(acc8[2]);
        pk.z = ((unsigned int)f2bf(acc8[5]) << 16) | f2bf(acc8[4]);
        pk.w = ((unsigned int)f2bf(acc8[7]) << 16) | f2bf(acc8[6]);
        *(uint4*)(Hb + (size_t)d * 64 + c16 * 4) = pk;
    }
}

// ---------------- GEMM (layers 2,3): A bf16 (Hb), single MFMA, fp8 out ----------------

__global__ __launch_bounds__(256) void k_gemm8(const unsigned short* __restrict__ A,
                                               const unsigned short* __restrict__ Wth,
                                               unsigned char* __restrict__ Fb,
                                               const float* __restrict__ al,
                                               const float* __restrict__ ar,
                                               float* __restrict__ el,
                                               float* __restrict__ er) {
    __shared__ unsigned char sg8[4][4096];   // per-wave fp8 staging (32 rows x 128 B)
    int t = threadIdx.x;
    int wave = t >> 6, lane = t & 63;
    int r = lane & 15, q = lane >> 4;
    int row0 = blockIdx.x * 128 + wave * 32;
    int rg0 = row0 + r, rg1 = row0 + 16 + r;

    f32x4 acc[2][8];
#pragma unroll
    for (int g = 0; g < 2; g++)
#pragma unroll
        for (int nt = 0; nt < 8; nt++) acc[g][nt] = (f32x4){0.f, 0.f, 0.f, 0.f};

#pragma unroll
    for (int ks = 0; ks < 4; ks++) {
        int k0 = ks * 32 + q * 8;
        bf16x8 a0 = {0, 0, 0, 0, 0, 0, 0, 0};
        bf16x8 a1 = {0, 0, 0, 0, 0, 0, 0, 0};
        if (rg0 < NN) a0 = *(const bf16x8*)(A + (size_t)rg0 * FD + k0);
        if (rg1 < NN) a1 = *(const bf16x8*)(A + (size_t)rg1 * FD + k0);
#pragma unroll
        for (int nt = 0; nt < 8; nt++) {
            int wo = ((nt * 16 + r) << 7) + k0;
            bf16x8 bh = *(const bf16x8*)(Wth + wo);
            acc[0][nt] = __builtin_amdgcn_mfma_f32_16x16x32_bf16(a0, bh, acc[0][nt], 0, 0, 0);
            acc[1][nt] = __builtin_amdgcn_mfma_f32_16x16x32_bf16(a1, bh, acc[1][nt], 0, 0, 0);
        }
    }
    epilogue(acc, row0, q, r, NN, al, ar, Fb, el, er, sg8[wave], lane);
}

// ---------------- fused agg (layer 3) + block-local max pool (4-wave barrier) ----------------

__global__ __launch_bounds__(256) void k_aggpool8(
        const unsigned char* __restrict__ Fb,
        const float* __restrict__ el, const float* __restrict__ er,
        const int* __restrict__ off, const int* __restrict__ deg_,
        const int* __restrict__ ssrc,
        float* __restrict__ partials) {
    __shared__ float wmax[4][128];
    int t = threadIdx.x;
    int wave = t >> 6, lane = t & 63;
    int c16 = lane & 15, g = lane >> 4;
    int d = blockIdx.x * 4 + wave;
    float acc8[8];
    if (d < NN) {
        agg_node(d, Fb, el, er, off, deg_, ssrc, lane, acc8);
    } else {
#pragma unroll
        for (int z = 0; z < 8; z++) acc8[z] = 0.f;
    }
    if (g == 0) {
#pragma unroll
        for (int z = 0; z < 8; z++) wmax[wave][c16 * 8 + z] = acc8[z];
    }
    __syncthreads();
    if (t < 128) {
        float m = fmaxf(fmaxf(wmax[0][t], wmax[1][t]), fmaxf(wmax[2][t], wmax[3][t]));
        partials[(size_t)blockIdx.x * 128 + t] = m;
    }
}

// ---------------- pool reduce: AB partial rows -> PBLK2 rows (contiguous chunks) ----------------

__global__ __launch_bounds__(128) void k_poolred(const float* __restrict__ partials,
                                                 float* __restrict__ partials2) {
    int c = threadIdx.x;         // channel 0..127
    int b = blockIdx.x;          // 0..PBLK2-1
    const int R = (AB + PBLK2 - 1) / PBLK2;   // 49
    int r0 = b * R, r1 = min(AB, r0 + R);
    float m = 0.f;
    for (int r = r0; r < r1; ++r)
        m = fmaxf(m, partials[(size_t)r * 128 + c]);
    partials2[(size_t)b * 128 + c] = m;
}

// ---------------- final: reduce partials2 + bf16-round + FC + softmax (1 block) ----------------

__global__ __launch_bounds__(1024) void k_final(const float* __restrict__ partials2,
                                                const float* __restrict__ Wfc,
                                                const float* __restrict__ bfc,
                                                float* __restrict__ outp) {
    __shared__ float red[1024];
    int t = threadIdx.x;
    int c = t & 127;             // channel
    int slice = t >> 7;          // 8 row-slices of 64 rows each
    float m = 0.f;
    int i0 = slice * (PBLK2 / 8);
#pragma unroll
    for (int k = 0; k < PBLK2 / 8; ++k)
        m = fmaxf(m, partials2[(size_t)(i0 + k) * 128 + c]);
    red[t] = m;
    __syncthreads();
    if (t < 128) {
        float v = red[t];
#pragma unroll
        for (int s = 1; s < 8; ++s) v = fmaxf(v, red[s * 128 + t]);
        // bf16-round the pooled value (matches the prior pipeline numerics)
        red[t] = __uint_as_float((unsigned int)f2bf(v) << 16);
    }
    __syncthreads();
    if (t < 64) {
        int j = t & 7;
        int kk = t >> 3;
        float partial = 0.f;
        for (int k = kk * 16; k < kk * 16 + 16; ++k) partial += red[k] * Wfc[k * 8 + j];
        for (int o = 8; o < 64; o <<= 1) partial += __shfl_xor(partial, o);
        float logit = partial + bfc[j];
        float mxl = logit;
        for (int o = 1; o < 8; o <<= 1) mxl = fmaxf(mxl, __shfl_xor(mxl, o));
        float ex = __expf(logit - mxl);
        float sm = ex;
        for (int o = 1; o < 8; o <<= 1) sm += __shfl_xor(sm, o);
        if (t < 8) outp[t] = ex / sm;
    }
}

// ---------------- launch ----------------

extern "C" void kernel_launch(void* const* d_in, const int* in_sizes, int n_in,
                              void* d_out, int out_size, void* d_ws, size_t ws_size,
                              hipStream_t stream) {
    const float* x   = (const float*)d_in[0];
    const int*   src = (const int*)d_in[1];
    const int*   dst = (const int*)d_in[2];
    const float* W1  = (const float*)d_in[3];
    const float* al1 = (const float*)d_in[4];
    const float* ar1 = (const float*)d_in[5];
    const float* W2  = (const float*)d_in[6];
    const float* al2 = (const float*)d_in[7];
    const float* ar2 = (const float*)d_in[8];
    const float* W3  = (const float*)d_in[9];
    const float* al3 = (const float*)d_in[10];
    const float* ar3 = (const float*)d_in[11];
    const float* Wfc = (const float*)d_in[12];
    const float* bfc = (const float*)d_in[13];
    float* out = (float*)d_out;

    char* p = (char*)d_ws;
    auto alloc = [&](size_t bytes) {
        char* r = p;
        p += (bytes + 255) & ~(size_t)255;
        return r;
    };
    unsigned char* Fb_a = (unsigned char*)alloc((size_t)NN * FD);   // fp8 features
    unsigned char* Fb_b = (unsigned char*)alloc((size_t)NN * FD);
    unsigned int*  Hb   = (unsigned int*)alloc((size_t)NN * 64 * 4); // bf16x2-packed H
    float* el_a   = (float*)alloc((size_t)NN * 4 * 4);
    float* er_a   = (float*)alloc((size_t)NN * 4 * 4);
    int*   off    = (int*)alloc((size_t)NN * 4);
    int*   deg    = (int*)alloc((size_t)NN * 4);
    int*   ssrc   = (int*)alloc((size_t)NB * CAP * 4);
    unsigned int* pairs = (unsigned int*)alloc((size_t)NB * CAP * 4);
    int*   gcur   = (int*)alloc((size_t)NB * 4);
    float* partials  = (float*)alloc((size_t)AB * 128 * 4);     // 12.8 MB
    float* partials2 = (float*)alloc((size_t)PBLK2 * 128 * 4);  // 256 KB
    unsigned short* Wth = (unsigned short*)alloc(3 * 16384 * 2);
    // pairs (7.5 MB) is dead after k_sortgemm1's bsort -> overlay layer-B el/er (3.2 MB)
    float* el_b = (float*)pairs;
    float* er_b = (float*)pairs + (size_t)NN * 4;

    const int BB = (NE + CHUNK - 1) / CHUNK;  // 196

    k_wsplit<<<192, 256, 0, stream>>>(W1, W2, W3, Wth, gcur);
    k_bucket<<<BB, 256, 0, stream>>>(src, dst, gcur, pairs);

    // bsort + layer-1 GEMM fused (independent work) -> Fb_a (fp8), el_a, er_a
    k_sortgemm1<<<NB + GB, 256, 0, stream>>>(pairs, gcur, off, deg, ssrc,
                                             x, Wth, Fb_a, al1, ar1, el_a, er_a);
    // layer-1 agg -> Hb (bf16)
    k_agg8<<<AB, 256, 0, stream>>>(Fb_a, el_a, er_a, off, deg, ssrc, Hb);
    // layer-2 GEMM: Hb -> Fb_b (fp8), el_b, er_b
    k_gemm8<<<GB, 256, 0, stream>>>((const unsigned short*)Hb, Wth + 16384,
                                    Fb_b, al2, ar2, el_b, er_b);
    // layer-2 agg -> Hb
    k_agg8<<<AB, 256, 0, stream>>>(Fb_b, el_b, er_b, off, deg, ssrc, Hb);
    // layer-3 GEMM: Hb -> Fb_a (fp8), el_a, er_a
    k_gemm8<<<GB, 256, 0, stream>>>((const unsigned short*)Hb, Wth + 32768,
                                    Fb_a, al3, ar3, el_a, er_a);
    // layer-3 agg + block-local max pool
    k_aggpool8<<<AB, 256, 0, stream>>>(Fb_a, el_a, er_a, off, deg, ssrc, partials);
    k_poolred<<<PBLK2, 128, 0, stream>>>(partials, partials2);
    k_final<<<1, 1024, 0, stream>>>(partials2, Wfc, bfc, out);
}

// Round 11
// 438.132 us; speedup vs baseline: 1.0092x; 1.0092x over previous
//
#include <hip/hip_runtime.h>

#define NN 100000   // nodes
#define NE 1600000  // edges
#define FD 128      // feature dim (4 heads x 32 ch); fp8 row = 128 B
#define NB 391      // ceil(NN/256) dst-buckets
#define CAP 4800    // padded bucket capacity (mean 4096, sigma 64 -> +11 sigma)
#define CHUNK 8192  // edges per k_bucket block -> 196 blocks
#define GB 782      // gemm tiles (128 rows each)
#define AB 25000    // agg blocks (4 nodes each, 1 node per wave)
#define PBLK2 512   // second-stage pool rows

typedef __attribute__((ext_vector_type(8))) short bf16x8;
typedef __attribute__((ext_vector_type(4))) float f32x4;
typedef __attribute__((ext_vector_type(2))) float f32x2;

union B8 { bf16x8 v; unsigned int u[4]; };

// ---------------- helpers ----------------

__device__ __forceinline__ unsigned short f2bf(float x) {
    unsigned int u = __float_as_uint(x);
    u += 0x7fffu + ((u >> 16) & 1u);   // round-to-nearest-even
    return (unsigned short)(u >> 16);
}

__device__ __forceinline__ unsigned char f2fp8(float x) {
    // low byte of packed fp8 conversion (RNE, saturating)
    return (unsigned char)__builtin_amdgcn_cvt_pk_fp8_f32(x, 0.f, 0u, false);
}

__device__ __forceinline__ unsigned int pkhi(unsigned int ua, unsigned int ub) {
    return __builtin_amdgcn_perm(ub, ua, 0x07060302);
}

// pack 8 f32 -> 8 bf16 (hi 16 bits, truncation — same grid as all passing rounds)
__device__ __forceinline__ bf16x8 pack8hi(const float4& x0, const float4& x1) {
    float f[8] = {x0.x, x0.y, x0.z, x0.w, x1.x, x1.y, x1.z, x1.w};
    B8 H;
#pragma unroll
    for (int i = 0; i < 4; i++) {
        unsigned int ua = __float_as_uint(f[2 * i]);
        unsigned int ub = __float_as_uint(f[2 * i + 1]);
        H.u[i] = pkhi(ua, ub);
    }
    return H.v;
}

// ---------------- W -> bf16 + gcur zeroing (one dispatch) ----------------

__global__ void k_wsplit(const float* __restrict__ W1, const float* __restrict__ W2,
                         const float* __restrict__ W3, unsigned short* __restrict__ Wth,
                         int* __restrict__ gcur) {
    int gid = blockIdx.x * 256 + threadIdx.x;  // 0..49151
    if (gid < NB) gcur[gid] = 0;
    int w = gid >> 14;
    int tid = gid & 16383;
    const float* W = (w == 0) ? W1 : (w == 1) ? W2 : W3;
    int n = tid >> 7, k = tid & 127;
    Wth[gid] = f2bf(W[k * 128 + n]);   // RNE bf16 weights
}

// ---------------- bucket scatter into padded per-bucket slots ----------------
// pairs[b*CAP + slot] = src | (dst&255)<<17

__global__ __launch_bounds__(256) void k_bucket(const int* __restrict__ src,
                                                const int* __restrict__ dst,
                                                int* __restrict__ gcur,
                                                unsigned int* __restrict__ pairs) {
    __shared__ int scnt[NB];
    __shared__ int sbase[NB];
    int t = threadIdx.x;
    for (int i = t; i < NB; i += 256) scnt[i] = 0;
    __syncthreads();
    int e0 = blockIdx.x * CHUNK, e1 = min(e0 + CHUNK, NE);
    for (int i = e0 + t; i < e1; i += 256) atomicAdd(&scnt[dst[i] >> 8], 1);
    __syncthreads();
    for (int i = t; i < NB; i += 256) {
        int c = scnt[i];
        sbase[i] = (c > 0) ? (i * CAP + atomicAdd(&gcur[i], c)) : 0;
        scnt[i] = 0;  // reuse as local cursor
    }
    __syncthreads();
    for (int i = e0 + t; i < e1; i += 256) {
        int d = dst[i];
        int b = d >> 8;
        int r = atomicAdd(&scnt[b], 1);
        pairs[sbase[b] + r] = (unsigned int)src[i] | ((unsigned int)(d & 255) << 17);
    }
}

// ---------------- per-bucket counting sort body ----------------

__device__ void bsort_body(int b, const unsigned int* __restrict__ pairs,
                           const int* __restrict__ gcur, int* __restrict__ off,
                           int* __restrict__ deg, int* __restrict__ ssrc) {
    __shared__ int hcnt[256];
    __shared__ int cur[256];
    int t = threadIdx.x;
    int cnt = gcur[b];
    int estart = b * CAP;
    hcnt[t] = 0;
    __syncthreads();
    for (int i = t; i < cnt; i += 256)
        atomicAdd(&hcnt[(pairs[estart + i] >> 17) & 255], 1);
    __syncthreads();
    int v = hcnt[t];
    cur[t] = v;
    __syncthreads();
    for (int o = 1; o < 256; o <<= 1) {
        int x = (t >= o) ? cur[t - o] : 0;
        __syncthreads();
        cur[t] += x;
        __syncthreads();
    }
    int excl = cur[t] - v;
    int node = (b << 8) + t;
    if (node < NN) {
        off[node] = estart + excl;
        deg[node] = v;
    }
    __syncthreads();
    cur[t] = estart + excl;
    __syncthreads();
    for (int i = t; i < cnt; i += 256) {
        unsigned int p = pairs[estart + i];
        int pos = atomicAdd(&cur[(p >> 17) & 255], 1);
        ssrc[pos] = (int)(p & 0x1ffffu);
    }
}

// ---------------- fused GEMM epilogue (2 row-groups): fp8 features + el/er ----------------
// Features staged as fp8 bytes in wave-private LDS, then copied out as uint4
// (coalesced) — avoids 1-byte scattered global stores (partial-line RMW).

__device__ __forceinline__ void epilogue(f32x4 acc[2][8], int row0, int q, int r, int nrows,
                                         const float* __restrict__ al,
                                         const float* __restrict__ ar,
                                         unsigned char* __restrict__ FbG,
                                         float* __restrict__ el, float* __restrict__ er,
                                         unsigned char* __restrict__ sg8, int lane) {
#pragma unroll
    for (int g = 0; g < 2; g++) {
#pragma unroll
        for (int i = 0; i < 4; i++) {
            int row_l = g * 16 + q * 4 + i;
            int row = row0 + row_l;
            float elp[4], erp[4];
#pragma unroll
            for (int h = 0; h < 4; h++) { elp[h] = 0.f; erp[h] = 0.f; }
#pragma unroll
            for (int nt = 0; nt < 8; nt++) {
                int h = nt >> 1;
                int c = ((nt & 1) << 4) + r;
                float v = acc[g][nt][i];
                elp[h] = fmaf(v, al[h * 32 + c], elp[h]);
                erp[h] = fmaf(v, ar[h * 32 + c], erp[h]);
            }
#pragma unroll
            for (int o = 1; o < 16; o <<= 1) {
#pragma unroll
                for (int h = 0; h < 4; h++) {
                    elp[h] += __shfl_xor(elp[h], o);
                    erp[h] += __shfl_xor(erp[h], o);
                }
            }
#pragma unroll
            for (int nt = 0; nt < 8; nt++)
                sg8[row_l * 128 + nt * 16 + r] = f2fp8(acc[g][nt][i]);
            if (row < nrows) {
                int hh = r & 3;
                float ve = (hh & 2) ? ((hh & 1) ? elp[3] : elp[2]) : ((hh & 1) ? elp[1] : elp[0]);
                float vr = (hh & 2) ? ((hh & 1) ? erp[3] : erp[2]) : ((hh & 1) ? erp[1] : erp[0]);
                if (r < 4) el[row * 4 + hh] = ve;
                else if (r < 8) er[row * 4 + hh] = vr;
            }
        }
    }
    // copy out the wave's 32 rows (4 KB), wave-private -> no barrier needed
#pragma unroll
    for (int it = 0; it < 4; it++) {
        int off = it * 1024 + lane * 16;
        int row = row0 + (off >> 7);
        uint4 v = *(const uint4*)(sg8 + off);
        if (row < nrows) *(uint4*)(FbG + (size_t)row * FD + (off & 127)) = v;
    }
}

// ---------------- GEMM body (layer 1): A f32 -> bf16, single MFMA per tile ----------------

__device__ void gemm_f32_body(int bid, const float* __restrict__ A,
                              const unsigned short* __restrict__ Wth,
                              unsigned char* __restrict__ Fb, int nrows,
                              const float* __restrict__ al, const float* __restrict__ ar,
                              float* __restrict__ el, float* __restrict__ er) {
    __shared__ unsigned char sg8[4][4096];   // per-wave fp8 staging (32 rows x 128 B)
    int t = threadIdx.x;
    int wave = t >> 6, lane = t & 63;
    int r = lane & 15, q = lane >> 4;
    int row0 = bid * 128 + wave * 32;
    int rg0 = row0 + r, rg1 = row0 + 16 + r;

    f32x4 acc[2][8];
#pragma unroll
    for (int g = 0; g < 2; g++)
#pragma unroll
        for (int nt = 0; nt < 8; nt++) acc[g][nt] = (f32x4){0.f, 0.f, 0.f, 0.f};

#pragma unroll
    for (int ks = 0; ks < 4; ks++) {
        int k0 = ks * 32 + q * 8;
        float4 z = make_float4(0.f, 0.f, 0.f, 0.f);
        float4 a0 = z, a1 = z, b0 = z, b1 = z;
        if (rg0 < nrows) {
            const float* pa = A + (size_t)rg0 * FD + k0;
            a0 = *(const float4*)pa;
            a1 = *(const float4*)(pa + 4);
        }
        if (rg1 < nrows) {
            const float* pb = A + (size_t)rg1 * FD + k0;
            b0 = *(const float4*)pb;
            b1 = *(const float4*)(pb + 4);
        }
        bf16x8 ah0 = pack8hi(a0, a1);
        bf16x8 ah1 = pack8hi(b0, b1);
#pragma unroll
        for (int nt = 0; nt < 8; nt++) {
            int wo = ((nt * 16 + r) << 7) + k0;
            bf16x8 bh = *(const bf16x8*)(Wth + wo);
            acc[0][nt] = __builtin_amdgcn_mfma_f32_16x16x32_bf16(ah0, bh, acc[0][nt], 0, 0, 0);
            acc[1][nt] = __builtin_amdgcn_mfma_f32_16x16x32_bf16(ah1, bh, acc[1][nt], 0, 0, 0);
        }
    }
    epilogue(acc, row0, q, r, nrows, al, ar, Fb, el, er, sg8[wave], lane);
}

// ---------------- fused dispatch: bsort (blocks 0..NB-1) + layer-1 GEMM (rest) ----------------

__global__ __launch_bounds__(256) void k_sortgemm1(const unsigned int* __restrict__ pairs,
                                                   const int* __restrict__ gcur,
                                                   int* __restrict__ off, int* __restrict__ deg,
                                                   int* __restrict__ ssrc,
                                                   const float* __restrict__ A,
                                                   const unsigned short* __restrict__ Wth,
                                                   unsigned char* __restrict__ Fb,
                                                   const float* __restrict__ al,
                                                   const float* __restrict__ ar,
                                                   float* __restrict__ el,
                                                   float* __restrict__ er) {
    int b = blockIdx.x;
    if (b < NB) bsort_body(b, pairs, gcur, off, deg, ssrc);
    else gemm_f32_body(b - NB, A, Wth, Fb, NN, al, ar, el, er);
}

// ---------------- wave-wide aggregation of one dst node (relu'd output) ----------------
// Features gathered as fp8 (8 B/lane), dequant via v_cvt_pk_f32_fp8, accumulated
// as f32x2 pairs (v_pk_fma_f32 path). Batch loop software-pipelined. Work-skip is
// a WAVE-UNIFORM branch between TWO fully-unrolled blocks (4-group / 2-group) —
// each block keeps its gathers batched (R10 lesson: a break inside the unroll
// kills load batching, -20%). Skipped groups have alpha = 0 -> bit-identical.
// Result: acc8[z] = relu(H[d][8*(lane&15)+z]), replicated across 4 lane-groups.

__device__ __forceinline__ void agg_node(int d,
        const unsigned char* __restrict__ Fb,
        const float* __restrict__ el, const float* __restrict__ er,
        const int* __restrict__ off, const int* __restrict__ deg_,
        const int* __restrict__ ssrc, int lane, float acc8[8]) {
    f32x2 acc2[4];
#pragma unroll
    for (int z = 0; z < 4; z++) acc2[z] = (f32x2){0.f, 0.f};
    int start = off[d];
    int dg = deg_[d];
    if (dg > 0) {
        int h = lane & 3;
        int eloc = lane >> 2;
        int g = lane >> 4;
        int c16 = lane & 15;
        int hsel2 = c16 >> 2;
        float er_h = er[d * 4 + h];
        float s = 0.f;
        // prefetch batch 0's edge data
        bool valid = (eloc < dg);
        int sid = valid ? ssrc[start + eloc] : 0;
        float elv = el[sid * 4 + h];        // sid=0 fallback: valid row, a=0 below
        for (int base = 0; base < dg; base += 16) {
            // alpha for the current batch (inputs prefetched last iteration)
            float v = elv + er_h;
            float e = fmaxf(v, 0.2f * v);   // leaky_relu, exact
            float a = valid ? __expf(e) : 0.f;
            int sidc = sid;
            // prefetch next batch's edge data (latency hides under FMA block)
            int i2 = base + 16 + eloc;
            valid = (i2 < dg);
            sid = valid ? ssrc[start + i2] : 0;
            elv = el[sid * 4 + h];
            s += a;
            int rem = dg - base;            // wave-uniform residual edge count
            if (rem > 8) {
                // full block: 4 row-groups, all 4 gathers issued up front
                uint2 u[4];
                float av[4];
#pragma unroll
                for (int k = 0; k < 4; k++) {
                    int sl = 16 * k + 4 * g;               // lane holding sid of row 4k+g
                    int sv = __shfl(sidc, sl, 64);
                    av[k] = __shfl(a, sl + hsel2, 64);     // alpha for my head
                    u[k] = *(const uint2*)(Fb + (size_t)sv * FD + c16 * 8);
                }
#pragma unroll
                for (int k = 0; k < 4; k++) {
                    f32x2 av2 = {av[k], av[k]};
                    f32x2 p0 = __builtin_amdgcn_cvt_pk_f32_fp8(u[k].x, false);
                    f32x2 p1 = __builtin_amdgcn_cvt_pk_f32_fp8(u[k].x, true);
                    f32x2 p2 = __builtin_amdgcn_cvt_pk_f32_fp8(u[k].y, false);
                    f32x2 p3 = __builtin_amdgcn_cvt_pk_f32_fp8(u[k].y, true);
                    acc2[0] = __builtin_elementwise_fma(p0, av2, acc2[0]);
                    acc2[1] = __builtin_elementwise_fma(p1, av2, acc2[1]);
                    acc2[2] = __builtin_elementwise_fma(p2, av2, acc2[2]);
                    acc2[3] = __builtin_elementwise_fma(p3, av2, acc2[3]);
                }
            } else {
                // short block: rows 8..15 all have alpha = 0 -> 2 row-groups only
                uint2 u[2];
                float av[2];
#pragma unroll
                for (int k = 0; k < 2; k++) {
                    int sl = 16 * k + 4 * g;
                    int sv = __shfl(sidc, sl, 64);
                    av[k] = __shfl(a, sl + hsel2, 64);
                    u[k] = *(const uint2*)(Fb + (size_t)sv * FD + c16 * 8);
                }
#pragma unroll
                for (int k = 0; k < 2; k++) {
                    f32x2 av2 = {av[k], av[k]};
                    f32x2 p0 = __builtin_amdgcn_cvt_pk_f32_fp8(u[k].x, false);
                    f32x2 p1 = __builtin_amdgcn_cvt_pk_f32_fp8(u[k].x, true);
                    f32x2 p2 = __builtin_amdgcn_cvt_pk_f32_fp8(u[k].y, false);
                    f32x2 p3 = __builtin_amdgcn_cvt_pk_f32_fp8(u[k].y, true);
                    acc2[0] = __builtin_elementwise_fma(p0, av2, acc2[0]);
                    acc2[1] = __builtin_elementwise_fma(p1, av2, acc2[1]);
                    acc2[2] = __builtin_elementwise_fma(p2, av2, acc2[2]);
                    acc2[3] = __builtin_elementwise_fma(p3, av2, acc2[3]);
                }
            }
        }
        float* accf = (float*)acc2;
        // merge the 4 row-groups (results become replicated wave-wide)
#pragma unroll
        for (int z = 0; z < 8; z++) {
            accf[z] += __shfl_xor(accf[z], 16, 64);
            accf[z] += __shfl_xor(accf[z], 32, 64);
        }
        for (int o = 4; o < 64; o <<= 1) s += __shfl_xor(s, o, 64);
        float inv = 1.f / __shfl(s, hsel2, 64);
#pragma unroll
        for (int z = 0; z < 8; z++) accf[z] *= inv;
    }
    float* accf = (float*)acc2;
#pragma unroll
    for (int z = 0; z < 8; z++) acc8[z] = fmaxf(accf[z], 0.f);   // relu (all 3 layers)
}

// ---------------- standalone agg: 4 waves/block, 1 node/wave, bf16 Hb out ----------------

__global__ __launch_bounds__(256) void k_agg8(
        const unsigned char* __restrict__ Fb,
        const float* __restrict__ el, const float* __restrict__ er,
        const int* __restrict__ off, const int* __restrict__ deg_,
        const int* __restrict__ ssrc,
        unsigned int* __restrict__ Hb) {
    int wave = threadIdx.x >> 6, lane = threadIdx.x & 63;
    int d = blockIdx.x * 4 + wave;
    if (d >= NN) return;
    float acc8[8];
    agg_node(d, Fb, el, er, off, deg_, ssrc, lane, acc8);
    int c16 = lane & 15, g = lane >> 4;
    if (g == 0) {   // 16 lanes write the packed bf16 row (256 B contiguous)
        uint4 pk;
        pk.x = ((unsigned int)f2bf(acc8[1]) << 16) | f2bf(acc8[0]);
        pk.y = ((unsigned int)f2bf(acc8[3]) << 16) | f2bf(acc8[2]);
        pk.z = ((unsigned int)f2bf(acc8[5]) << 16) | f2bf(acc8[4]);
        pk.w = ((unsigned int)f2bf(acc8[7]) << 16) | f2bf(acc8[6]);
        *(uint4*)(Hb + (size_t)d * 64 + c16 * 4) = pk;
    }
}

// ---------------- GEMM (layers 2,3): A bf16 (Hb), single MFMA, fp8 out ----------------

__global__ __launch_bounds__(256) void k_gemm8(const unsigned short* __restrict__ A,
                                               const unsigned short* __restrict__ Wth,
                                               unsigned char* __restrict__ Fb,
                                               const float* __restrict__ al,
                                               const float* __restrict__ ar,
                                               float* __restrict__ el,
                                               float* __restrict__ er) {
    __shared__ unsigned char sg8[4][4096];   // per-wave fp8 staging (32 rows x 128 B)
    int t = threadIdx.x;
    int wave = t >> 6, lane = t & 63;
    int r = lane & 15, q = lane >> 4;
    int row0 = blockIdx.x * 128 + wave * 32;
    int rg0 = row0 + r, rg1 = row0 + 16 + r;

    f32x4 acc[2][8];
#pragma unroll
    for (int g = 0; g < 2; g++)
#pragma unroll
        for (int nt = 0; nt < 8; nt++) acc[g][nt] = (f32x4){0.f, 0.f, 0.f, 0.f};

#pragma unroll
    for (int ks = 0; ks < 4; ks++) {
        int k0 = ks * 32 + q * 8;
        bf16x8 a0 = {0, 0, 0, 0, 0, 0, 0, 0};
        bf16x8 a1 = {0, 0, 0, 0, 0, 0, 0, 0};
        if (rg0 < NN) a0 = *(const bf16x8*)(A + (size_t)rg0 * FD + k0);
        if (rg1 < NN) a1 = *(const bf16x8*)(A + (size_t)rg1 * FD + k0);
#pragma unroll
        for (int nt = 0; nt < 8; nt++) {
            int wo = ((nt * 16 + r) << 7) + k0;
            bf16x8 bh = *(const bf16x8*)(Wth + wo);
            acc[0][nt] = __builtin_amdgcn_mfma_f32_16x16x32_bf16(a0, bh, acc[0][nt], 0, 0, 0);
            acc[1][nt] = __builtin_amdgcn_mfma_f32_16x16x32_bf16(a1, bh, acc[1][nt], 0, 0, 0);
        }
    }
    epilogue(acc, row0, q, r, NN, al, ar, Fb, el, er, sg8[wave], lane);
}

// ---------------- fused agg (layer 3) + block-local max pool (4-wave barrier) ----------------

__global__ __launch_bounds__(256) void k_aggpool8(
        const unsigned char* __restrict__ Fb,
        const float* __restrict__ el, const float* __restrict__ er,
        const int* __restrict__ off, const int* __restrict__ deg_,
        const int* __restrict__ ssrc,
        float* __restrict__ partials) {
    __shared__ float wmax[4][128];
    int t = threadIdx.x;
    int wave = t >> 6, lane = t & 63;
    int c16 = lane & 15, g = lane >> 4;
    int d = blockIdx.x * 4 + wave;
    float acc8[8];
    if (d < NN) {
        agg_node(d, Fb, el, er, off, deg_, ssrc, lane, acc8);
    } else {
#pragma unroll
        for (int z = 0; z < 8; z++) acc8[z] = 0.f;
    }
    if (g == 0) {
#pragma unroll
        for (int z = 0; z < 8; z++) wmax[wave][c16 * 8 + z] = acc8[z];
    }
    __syncthreads();
    if (t < 128) {
        float m = fmaxf(fmaxf(wmax[0][t], wmax[1][t]), fmaxf(wmax[2][t], wmax[3][t]));
        partials[(size_t)blockIdx.x * 128 + t] = m;
    }
}

// ---------------- pool reduce: AB partial rows -> PBLK2 rows (contiguous chunks) ----------------

__global__ __launch_bounds__(128) void k_poolred(const float* __restrict__ partials,
                                                 float* __restrict__ partials2) {
    int c = threadIdx.x;         // channel 0..127
    int b = blockIdx.x;          // 0..PBLK2-1
    const int R = (AB + PBLK2 - 1) / PBLK2;   // 49
    int r0 = b * R, r1 = min(AB, r0 + R);
    float m = 0.f;
    for (int r = r0; r < r1; ++r)
        m = fmaxf(m, partials[(size_t)r * 128 + c]);
    partials2[(size_t)b * 128 + c] = m;
}

// ---------------- final: reduce partials2 + bf16-round + FC + softmax (1 block) ----------------

__global__ __launch_bounds__(1024) void k_final(const float* __restrict__ partials2,
                                                const float* __restrict__ Wfc,
                                                const float* __restrict__ bfc,
                                                float* __restrict__ outp) {
    __shared__ float red[1024];
    int t = threadIdx.x;
    int c = t & 127;             // channel
    int slice = t >> 7;          // 8 row-slices of 64 rows each
    float m = 0.f;
    int i0 = slice * (PBLK2 / 8);
#pragma unroll
    for (int k = 0; k < PBLK2 / 8; ++k)
        m = fmaxf(m, partials2[(size_t)(i0 + k) * 128 + c]);
    red[t] = m;
    __syncthreads();
    if (t < 128) {
        float v = red[t];
#pragma unroll
        for (int s = 1; s < 8; ++s) v = fmaxf(v, red[s * 128 + t]);
        // bf16-round the pooled value (matches the prior pipeline numerics)
        red[t] = __uint_as_float((unsigned int)f2bf(v) << 16);
    }
    __syncthreads();
    if (t < 64) {
        int j = t & 7;
        int kk = t >> 3;
        float partial = 0.f;
        for (int k = kk * 16; k < kk * 16 + 16; ++k) partial += red[k] * Wfc[k * 8 + j];
        for (int o = 8; o < 64; o <<= 1) partial += __shfl_xor(partial, o);
        float logit = partial + bfc[j];
        float mxl = logit;
        for (int o = 1; o < 8; o <<= 1) mxl = fmaxf(mxl, __shfl_xor(mxl, o));
        float ex = __expf(logit - mxl);
        float sm = ex;
        for (int o = 1; o < 8; o <<= 1) sm += __shfl_xor(sm, o);
        if (t < 8) outp[t] = ex / sm;
    }
}

// ---------------- launch ----------------

extern "C" void kernel_launch(void* const* d_in, const int* in_sizes, int n_in,
                              void* d_out, int out_size, void* d_ws, size_t ws_size,
                              hipStream_t stream) {
    const float* x   = (const float*)d_in[0];
    const int*   src = (const int*)d_in[1];
    const int*   dst = (const int*)d_in[2];
    const float* W1  = (const float*)d_in[3];
    const float* al1 = (const float*)d_in[4];
    const float* ar1 = (const float*)d_in[5];
    const float* W2  = (const float*)d_in[6];
    const float* al2 = (const float*)d_in[7];
    const float* ar2 = (const float*)d_in[8];
    const float* W3  = (const float*)d_in[9];
    const float* al3 = (const float*)d_in[10];
    const float* ar3 = (const float*)d_in[11];
    const float* Wfc = (const float*)d_in[12];
    const float* bfc = (const float*)d_in[13];
    float* out = (float*)d_out;

    char* p = (char*)d_ws;
    auto alloc = [&](size_t bytes) {
        char* r = p;
        p += (bytes + 255) & ~(size_t)255;
        return r;
    };
    unsigned char* Fb_a = (unsigned char*)alloc((size_t)NN * FD);   // fp8 features
    unsigned char* Fb_b = (unsigned char*)alloc((size_t)NN * FD);
    unsigned int*  Hb   = (unsigned int*)alloc((size_t)NN * 64 * 4); // bf16x2-packed H
    float* el_a   = (float*)alloc((size_t)NN * 4 * 4);
    float* er_a   = (float*)alloc((size_t)NN * 4 * 4);
    int*   off    = (int*)alloc((size_t)NN * 4);
    int*   deg    = (int*)alloc((size_t)NN * 4);
    int*   ssrc   = (int*)alloc((size_t)NB * CAP * 4);
    unsigned int* pairs = (unsigned int*)alloc((size_t)NB * CAP * 4);
    int*   gcur   = (int*)alloc((size_t)NB * 4);
    float* partials  = (float*)alloc((size_t)AB * 128 * 4);     // 12.8 MB
    float* partials2 = (float*)alloc((size_t)PBLK2 * 128 * 4);  // 256 KB
    unsigned short* Wth = (unsigned short*)alloc(3 * 16384 * 2);
    // pairs (7.5 MB) is dead after k_sortgemm1's bsort -> overlay layer-B el/er (3.2 MB)
    float* el_b = (float*)pairs;
    float* er_b = (float*)pairs + (size_t)NN * 4;

    const int BB = (NE + CHUNK - 1) / CHUNK;  // 196

    k_wsplit<<<192, 256, 0, stream>>>(W1, W2, W3, Wth, gcur);
    k_bucket<<<BB, 256, 0, stream>>>(src, dst, gcur, pairs);

    // bsort + layer-1 GEMM fused (independent work) -> Fb_a (fp8), el_a, er_a
    k_sortgemm1<<<NB + GB, 256, 0, stream>>>(pairs, gcur, off, deg, ssrc,
                                             x, Wth, Fb_a, al1, ar1, el_a, er_a);
    // layer-1 agg -> Hb (bf16)
    k_agg8<<<AB, 256, 0, stream>>>(Fb_a, el_a, er_a, off, deg, ssrc, Hb);
    // layer-2 GEMM: Hb -> Fb_b (fp8), el_b, er_b
    k_gemm8<<<GB, 256, 0, stream>>>((const unsigned short*)Hb, Wth + 16384,
                                    Fb_b, al2, ar2, el_b, er_b);
    // layer-2 agg -> Hb
    k_agg8<<<AB, 256, 0, stream>>>(Fb_b, el_b, er_b, off, deg, ssrc, Hb);
    // layer-3 GEMM: Hb -> Fb_a (fp8), el_a, er_a
    k_gemm8<<<GB, 256, 0, stream>>>((const unsigned short*)Hb, Wth + 32768,
                                    Fb_a, al3, ar3, el_a, er_a);
    // layer-3 agg + block-local max pool
    k_aggpool8<<<AB, 256, 0, stream>>>(Fb_a, el_a, er_a, off, deg, ssrc, partials);
    k_poolred<<<PBLK2, 128, 0, stream>>>(partials, partials2);
    k_final<<<1, 1024, 0, stream>>>(partials2, Wfc, bfc, out);
}

// Round 12
// 409.243 us; speedup vs baseline: 1.0804x; 1.0706x over previous
//
#include <hip/hip_runtime.h>

#define NN 100000   // nodes
#define NE 1600000  // edges
#define FD 128      // feature dim (4 heads x 32 ch); fp8 row = 128 B
#define NB 391      // ceil(NN/256) dst-buckets
#define CAP 4800    // padded bucket capacity (mean 4096, sigma 64 -> +11 sigma)
#define CHUNK 8192  // edges per k_bucket block -> 196 blocks
#define GB 782      // gemm tiles (128 rows each)
#define AB 25000    // agg blocks (4 nodes each, 1 node per wave)
#define PBLK2 512   // second-stage pool rows

typedef __attribute__((ext_vector_type(8))) short bf16x8;
typedef __attribute__((ext_vector_type(4))) float f32x4;
typedef __attribute__((ext_vector_type(2))) float f32x2;

union B8 { bf16x8 v; unsigned int u[4]; };

// ---------------- helpers ----------------

__device__ __forceinline__ unsigned short f2bf(float x) {
    unsigned int u = __float_as_uint(x);
    u += 0x7fffu + ((u >> 16) & 1u);   // round-to-nearest-even
    return (unsigned short)(u >> 16);
}

__device__ __forceinline__ unsigned char f2fp8(float x) {
    // low byte of packed fp8 conversion (RNE, saturating)
    return (unsigned char)__builtin_amdgcn_cvt_pk_fp8_f32(x, 0.f, 0u, false);
}

__device__ __forceinline__ unsigned int pkhi(unsigned int ua, unsigned int ub) {
    return __builtin_amdgcn_perm(ub, ua, 0x07060302);
}

// pack 8 f32 -> 8 bf16 (hi 16 bits, truncation — same grid as all passing rounds)
__device__ __forceinline__ bf16x8 pack8hi(const float4& x0, const float4& x1) {
    float f[8] = {x0.x, x0.y, x0.z, x0.w, x1.x, x1.y, x1.z, x1.w};
    B8 H;
#pragma unroll
    for (int i = 0; i < 4; i++) {
        unsigned int ua = __float_as_uint(f[2 * i]);
        unsigned int ub = __float_as_uint(f[2 * i + 1]);
        H.u[i] = pkhi(ua, ub);
    }
    return H.v;
}

// ---------------- W -> bf16 + gcur zeroing (one dispatch) ----------------

__global__ void k_wsplit(const float* __restrict__ W1, const float* __restrict__ W2,
                         const float* __restrict__ W3, unsigned short* __restrict__ Wth,
                         int* __restrict__ gcur) {
    int gid = blockIdx.x * 256 + threadIdx.x;  // 0..49151
    if (gid < NB) gcur[gid] = 0;
    int w = gid >> 14;
    int tid = gid & 16383;
    const float* W = (w == 0) ? W1 : (w == 1) ? W2 : W3;
    int n = tid >> 7, k = tid & 127;
    Wth[gid] = f2bf(W[k * 128 + n]);   // RNE bf16 weights
}

// ---------------- bucket scatter into padded per-bucket slots ----------------
// pairs[b*CAP + slot] = src | (dst&255)<<17

__global__ __launch_bounds__(256) void k_bucket(const int* __restrict__ src,
                                                const int* __restrict__ dst,
                                                int* __restrict__ gcur,
                                                unsigned int* __restrict__ pairs) {
    __shared__ int scnt[NB];
    __shared__ int sbase[NB];
    int t = threadIdx.x;
    for (int i = t; i < NB; i += 256) scnt[i] = 0;
    __syncthreads();
    int e0 = blockIdx.x * CHUNK, e1 = min(e0 + CHUNK, NE);
    for (int i = e0 + t; i < e1; i += 256) atomicAdd(&scnt[dst[i] >> 8], 1);
    __syncthreads();
    for (int i = t; i < NB; i += 256) {
        int c = scnt[i];
        sbase[i] = (c > 0) ? (i * CAP + atomicAdd(&gcur[i], c)) : 0;
        scnt[i] = 0;  // reuse as local cursor
    }
    __syncthreads();
    for (int i = e0 + t; i < e1; i += 256) {
        int d = dst[i];
        int b = d >> 8;
        int r = atomicAdd(&scnt[b], 1);
        pairs[sbase[b] + r] = (unsigned int)src[i] | ((unsigned int)(d & 255) << 17);
    }
}

// ---------------- per-bucket counting sort body ----------------

__device__ void bsort_body(int b, const unsigned int* __restrict__ pairs,
                           const int* __restrict__ gcur, int* __restrict__ off,
                           int* __restrict__ deg, int* __restrict__ ssrc) {
    __shared__ int hcnt[256];
    __shared__ int cur[256];
    int t = threadIdx.x;
    int cnt = gcur[b];
    int estart = b * CAP;
    hcnt[t] = 0;
    __syncthreads();
    for (int i = t; i < cnt; i += 256)
        atomicAdd(&hcnt[(pairs[estart + i] >> 17) & 255], 1);
    __syncthreads();
    int v = hcnt[t];
    cur[t] = v;
    __syncthreads();
    for (int o = 1; o < 256; o <<= 1) {
        int x = (t >= o) ? cur[t - o] : 0;
        __syncthreads();
        cur[t] += x;
        __syncthreads();
    }
    int excl = cur[t] - v;
    int node = (b << 8) + t;
    if (node < NN) {
        off[node] = estart + excl;
        deg[node] = v;
    }
    __syncthreads();
    cur[t] = estart + excl;
    __syncthreads();
    for (int i = t; i < cnt; i += 256) {
        unsigned int p = pairs[estart + i];
        int pos = atomicAdd(&cur[(p >> 17) & 255], 1);
        ssrc[pos] = (int)(p & 0x1ffffu);
    }
}

// ---------------- fused GEMM epilogue (2 row-groups): fp8 features + el/er ----------------
// Features staged as fp8 bytes in wave-private LDS, then copied out as uint4
// (coalesced) — avoids 1-byte scattered global stores (partial-line RMW).

__device__ __forceinline__ void epilogue(f32x4 acc[2][8], int row0, int q, int r, int nrows,
                                         const float* __restrict__ al,
                                         const float* __restrict__ ar,
                                         unsigned char* __restrict__ FbG,
                                         float* __restrict__ el, float* __restrict__ er,
                                         unsigned char* __restrict__ sg8, int lane) {
#pragma unroll
    for (int g = 0; g < 2; g++) {
#pragma unroll
        for (int i = 0; i < 4; i++) {
            int row_l = g * 16 + q * 4 + i;
            int row = row0 + row_l;
            float elp[4], erp[4];
#pragma unroll
            for (int h = 0; h < 4; h++) { elp[h] = 0.f; erp[h] = 0.f; }
#pragma unroll
            for (int nt = 0; nt < 8; nt++) {
                int h = nt >> 1;
                int c = ((nt & 1) << 4) + r;
                float v = acc[g][nt][i];
                elp[h] = fmaf(v, al[h * 32 + c], elp[h]);
                erp[h] = fmaf(v, ar[h * 32 + c], erp[h]);
            }
#pragma unroll
            for (int o = 1; o < 16; o <<= 1) {
#pragma unroll
                for (int h = 0; h < 4; h++) {
                    elp[h] += __shfl_xor(elp[h], o);
                    erp[h] += __shfl_xor(erp[h], o);
                }
            }
#pragma unroll
            for (int nt = 0; nt < 8; nt++)
                sg8[row_l * 128 + nt * 16 + r] = f2fp8(acc[g][nt][i]);
            if (row < nrows) {
                int hh = r & 3;
                float ve = (hh & 2) ? ((hh & 1) ? elp[3] : elp[2]) : ((hh & 1) ? elp[1] : elp[0]);
                float vr = (hh & 2) ? ((hh & 1) ? erp[3] : erp[2]) : ((hh & 1) ? erp[1] : erp[0]);
                if (r < 4) el[row * 4 + hh] = ve;
                else if (r < 8) er[row * 4 + hh] = vr;
            }
        }
    }
    // copy out the wave's 32 rows (4 KB), wave-private -> no barrier needed
#pragma unroll
    for (int it = 0; it < 4; it++) {
        int off = it * 1024 + lane * 16;
        int row = row0 + (off >> 7);
        uint4 v = *(const uint4*)(sg8 + off);
        if (row < nrows) *(uint4*)(FbG + (size_t)row * FD + (off & 127)) = v;
    }
}

// ---------------- GEMM body (layer 1): A f32 -> bf16, single MFMA per tile ----------------

__device__ void gemm_f32_body(int bid, const float* __restrict__ A,
                              const unsigned short* __restrict__ Wth,
                              unsigned char* __restrict__ Fb, int nrows,
                              const float* __restrict__ al, const float* __restrict__ ar,
                              float* __restrict__ el, float* __restrict__ er) {
    __shared__ unsigned char sg8[4][4096];   // per-wave fp8 staging (32 rows x 128 B)
    int t = threadIdx.x;
    int wave = t >> 6, lane = t & 63;
    int r = lane & 15, q = lane >> 4;
    int row0 = bid * 128 + wave * 32;
    int rg0 = row0 + r, rg1 = row0 + 16 + r;

    f32x4 acc[2][8];
#pragma unroll
    for (int g = 0; g < 2; g++)
#pragma unroll
        for (int nt = 0; nt < 8; nt++) acc[g][nt] = (f32x4){0.f, 0.f, 0.f, 0.f};

#pragma unroll
    for (int ks = 0; ks < 4; ks++) {
        int k0 = ks * 32 + q * 8;
        float4 z = make_float4(0.f, 0.f, 0.f, 0.f);
        float4 a0 = z, a1 = z, b0 = z, b1 = z;
        if (rg0 < nrows) {
            const float* pa = A + (size_t)rg0 * FD + k0;
            a0 = *(const float4*)pa;
            a1 = *(const float4*)(pa + 4);
        }
        if (rg1 < nrows) {
            const float* pb = A + (size_t)rg1 * FD + k0;
            b0 = *(const float4*)pb;
            b1 = *(const float4*)(pb + 4);
        }
        bf16x8 ah0 = pack8hi(a0, a1);
        bf16x8 ah1 = pack8hi(b0, b1);
#pragma unroll
        for (int nt = 0; nt < 8; nt++) {
            int wo = ((nt * 16 + r) << 7) + k0;
            bf16x8 bh = *(const bf16x8*)(Wth + wo);
            acc[0][nt] = __builtin_amdgcn_mfma_f32_16x16x32_bf16(ah0, bh, acc[0][nt], 0, 0, 0);
            acc[1][nt] = __builtin_amdgcn_mfma_f32_16x16x32_bf16(ah1, bh, acc[1][nt], 0, 0, 0);
        }
    }
    epilogue(acc, row0, q, r, nrows, al, ar, Fb, el, er, sg8[wave], lane);
}

// ---------------- fused dispatch: bsort (blocks 0..NB-1) + layer-1 GEMM (rest) ----------------

__global__ __launch_bounds__(256) void k_sortgemm1(const unsigned int* __restrict__ pairs,
                                                   const int* __restrict__ gcur,
                                                   int* __restrict__ off, int* __restrict__ deg,
                                                   int* __restrict__ ssrc,
                                                   const float* __restrict__ A,
                                                   const unsigned short* __restrict__ Wth,
                                                   unsigned char* __restrict__ Fb,
                                                   const float* __restrict__ al,
                                                   const float* __restrict__ ar,
                                                   float* __restrict__ el,
                                                   float* __restrict__ er) {
    int b = blockIdx.x;
    if (b < NB) bsort_body(b, pairs, gcur, off, deg, ssrc);
    else gemm_f32_body(b - NB, A, Wth, Fb, NN, al, ar, el, er);
}

// ---------------- wave-wide aggregation of one dst node (relu'd output) ----------------
// R9 optimum, restored verbatim. Features gathered as fp8 (8 B/lane), dequant via
// v_cvt_pk_f32_fp8, accumulated as f32x2 pairs (v_pk_fma_f32 path). Batch loop
// software-pipelined: next batch's sid/el prefetched during the current batch's
// FMA block; all 4 row loads issued before any cvt/fma (4 loads in flight/lane).
// STRAIGHT-LINE BODY ONLY: R10 (divergent break) and R11 (uniform dual-path) both
// regressed ~15-20% — any control flow in this loop defeats cross-iteration
// scheduling and costs more than the alpha=0 work it skips.
// Result: acc8[z] = relu(H[d][8*(lane&15)+z]), replicated across 4 lane-groups.

__device__ __forceinline__ void agg_node(int d,
        const unsigned char* __restrict__ Fb,
        const float* __restrict__ el, const float* __restrict__ er,
        const int* __restrict__ off, const int* __restrict__ deg_,
        const int* __restrict__ ssrc, int lane, float acc8[8]) {
    f32x2 acc2[4];
#pragma unroll
    for (int z = 0; z < 4; z++) acc2[z] = (f32x2){0.f, 0.f};
    int start = off[d];
    int dg = deg_[d];
    if (dg > 0) {
        int h = lane & 3;
        int eloc = lane >> 2;
        int g = lane >> 4;
        int c16 = lane & 15;
        int hsel2 = c16 >> 2;
        float er_h = er[d * 4 + h];
        float s = 0.f;
        // prefetch batch 0's edge data
        bool valid = (eloc < dg);
        int sid = valid ? ssrc[start + eloc] : 0;
        float elv = el[sid * 4 + h];        // sid=0 fallback: valid row, a=0 below
        for (int base = 0; base < dg; base += 16) {
            // alpha for the current batch (inputs prefetched last iteration)
            float v = elv + er_h;
            float e = fmaxf(v, 0.2f * v);   // leaky_relu, exact
            float a = valid ? __expf(e) : 0.f;
            int sidc = sid;
            // prefetch next batch's edge data (latency hides under FMA block)
            int i2 = base + 16 + eloc;
            valid = (i2 < dg);
            sid = valid ? ssrc[start + i2] : 0;
            elv = el[sid * 4 + h];
            s += a;
            // broadcast sids/alphas; issue all 4 feature loads up front
            uint2 u[4];
            float av[4];
#pragma unroll
            for (int k = 0; k < 4; k++) {
                int sl = 16 * k + 4 * g;               // lane holding sid of row 4k+g
                int sv = __shfl(sidc, sl, 64);
                av[k] = __shfl(a, sl + hsel2, 64);     // alpha for my head
                u[k] = *(const uint2*)(Fb + (size_t)sv * FD + c16 * 8);
            }
#pragma unroll
            for (int k = 0; k < 4; k++) {
                f32x2 av2 = {av[k], av[k]};
                f32x2 p0 = __builtin_amdgcn_cvt_pk_f32_fp8(u[k].x, false);
                f32x2 p1 = __builtin_amdgcn_cvt_pk_f32_fp8(u[k].x, true);
                f32x2 p2 = __builtin_amdgcn_cvt_pk_f32_fp8(u[k].y, false);
                f32x2 p3 = __builtin_amdgcn_cvt_pk_f32_fp8(u[k].y, true);
                acc2[0] = __builtin_elementwise_fma(p0, av2, acc2[0]);
                acc2[1] = __builtin_elementwise_fma(p1, av2, acc2[1]);
                acc2[2] = __builtin_elementwise_fma(p2, av2, acc2[2]);
                acc2[3] = __builtin_elementwise_fma(p3, av2, acc2[3]);
            }
        }
        float* accf = (float*)acc2;
        // merge the 4 row-groups (results become replicated wave-wide)
#pragma unroll
        for (int z = 0; z < 8; z++) {
            accf[z] += __shfl_xor(accf[z], 16, 64);
            accf[z] += __shfl_xor(accf[z], 32, 64);
        }
        for (int o = 4; o < 64; o <<= 1) s += __shfl_xor(s, o, 64);
        float inv = 1.f / __shfl(s, hsel2, 64);
#pragma unroll
        for (int z = 0; z < 8; z++) accf[z] *= inv;
    }
    float* accf = (float*)acc2;
#pragma unroll
    for (int z = 0; z < 8; z++) acc8[z] = fmaxf(accf[z], 0.f);   // relu (all 3 layers)
}

// ---------------- standalone agg: 4 waves/block, 1 node/wave, bf16 Hb out ----------------

__global__ __launch_bounds__(256) void k_agg8(
        const unsigned char* __restrict__ Fb,
        const float* __restrict__ el, const float* __restrict__ er,
        const int* __restrict__ off, const int* __restrict__ deg_,
        const int* __restrict__ ssrc,
        unsigned int* __restrict__ Hb) {
    int wave = threadIdx.x >> 6, lane = threadIdx.x & 63;
    int d = blockIdx.x * 4 + wave;
    if (d >= NN) return;
    float acc8[8];
    agg_node(d, Fb, el, er, off, deg_, ssrc, lane, acc8);
    int c16 = lane & 15, g = lane >> 4;
    if (g == 0) {   // 16 lanes write the packed bf16 row (256 B contiguous)
        uint4 pk;
        pk.x = ((unsigned int)f2bf(acc8[1]) << 16) | f2bf(acc8[0]);
        pk.y = ((unsigned int)f2bf(acc8[3]) << 16) | f2bf(acc8[2]);
        pk.z = ((unsigned int)f2bf(acc8[5]) << 16) | f2bf(acc8[4]);
        pk.w = ((unsigned int)f2bf(acc8[7]) << 16) | f2bf(acc8[6]);
        *(uint4*)(Hb + (size_t)d * 64 + c16 * 4) = pk;
    }
}

// ---------------- GEMM (layers 2,3): A bf16 (Hb), single MFMA, fp8 out ----------------

__global__ __launch_bounds__(256) void k_gemm8(const unsigned short* __restrict__ A,
                                               const unsigned short* __restrict__ Wth,
                                               unsigned char* __restrict__ Fb,
                                               const float* __restrict__ al,
                                               const float* __restrict__ ar,
                                               float* __restrict__ el,
                                               float* __restrict__ er) {
    __shared__ unsigned char sg8[4][4096];   // per-wave fp8 staging (32 rows x 128 B)
    int t = threadIdx.x;
    int wave = t >> 6, lane = t & 63;
    int r = lane & 15, q = lane >> 4;
    int row0 = blockIdx.x * 128 + wave * 32;
    int rg0 = row0 + r, rg1 = row0 + 16 + r;

    f32x4 acc[2][8];
#pragma unroll
    for (int g = 0; g < 2; g++)
#pragma unroll
        for (int nt = 0; nt < 8; nt++) acc[g][nt] = (f32x4){0.f, 0.f, 0.f, 0.f};

#pragma unroll
    for (int ks = 0; ks < 4; ks++) {
        int k0 = ks * 32 + q * 8;
        bf16x8 a0 = {0, 0, 0, 0, 0, 0, 0, 0};
        bf16x8 a1 = {0, 0, 0, 0, 0, 0, 0, 0};
        if (rg0 < NN) a0 = *(const bf16x8*)(A + (size_t)rg0 * FD + k0);
        if (rg1 < NN) a1 = *(const bf16x8*)(A + (size_t)rg1 * FD + k0);
#pragma unroll
        for (int nt = 0; nt < 8; nt++) {
            int wo = ((nt * 16 + r) << 7) + k0;
            bf16x8 bh = *(const bf16x8*)(Wth + wo);
            acc[0][nt] = __builtin_amdgcn_mfma_f32_16x16x32_bf16(a0, bh, acc[0][nt], 0, 0, 0);
            acc[1][nt] = __builtin_amdgcn_mfma_f32_16x16x32_bf16(a1, bh, acc[1][nt], 0, 0, 0);
        }
    }
    epilogue(acc, row0, q, r, NN, al, ar, Fb, el, er, sg8[wave], lane);
}

// ---------------- fused agg (layer 3) + block-local max pool (4-wave barrier) ----------------

__global__ __launch_bounds__(256) void k_aggpool8(
        const unsigned char* __restrict__ Fb,
        const float* __restrict__ el, const float* __restrict__ er,
        const int* __restrict__ off, const int* __restrict__ deg_,
        const int* __restrict__ ssrc,
        float* __restrict__ partials) {
    __shared__ float wmax[4][128];
    int t = threadIdx.x;
    int wave = t >> 6, lane = t & 63;
    int c16 = lane & 15, g = lane >> 4;
    int d = blockIdx.x * 4 + wave;
    float acc8[8];
    if (d < NN) {
        agg_node(d, Fb, el, er, off, deg_, ssrc, lane, acc8);
    } else {
#pragma unroll
        for (int z = 0; z < 8; z++) acc8[z] = 0.f;
    }
    if (g == 0) {
#pragma unroll
        for (int z = 0; z < 8; z++) wmax[wave][c16 * 8 + z] = acc8[z];
    }
    __syncthreads();
    if (t < 128) {
        float m = fmaxf(fmaxf(wmax[0][t], wmax[1][t]), fmaxf(wmax[2][t], wmax[3][t]));
        partials[(size_t)blockIdx.x * 128 + t] = m;
    }
}

// ---------------- pool reduce: AB partial rows -> PBLK2 rows (contiguous chunks) ----------------

__global__ __launch_bounds__(128) void k_poolred(const float* __restrict__ partials,
                                                 float* __restrict__ partials2) {
    int c = threadIdx.x;         // channel 0..127
    int b = blockIdx.x;          // 0..PBLK2-1
    const int R = (AB + PBLK2 - 1) / PBLK2;   // 49
    int r0 = b * R, r1 = min(AB, r0 + R);
    float m = 0.f;
    for (int r = r0; r < r1; ++r)
        m = fmaxf(m, partials[(size_t)r * 128 + c]);
    partials2[(size_t)b * 128 + c] = m;
}

// ---------------- final: reduce partials2 + bf16-round + FC + softmax (1 block) ----------------

__global__ __launch_bounds__(1024) void k_final(const float* __restrict__ partials2,
                                                const float* __restrict__ Wfc,
                                                const float* __restrict__ bfc,
                                                float* __restrict__ outp) {
    __shared__ float red[1024];
    int t = threadIdx.x;
    int c = t & 127;             // channel
    int slice = t >> 7;          // 8 row-slices of 64 rows each
    float m = 0.f;
    int i0 = slice * (PBLK2 / 8);
#pragma unroll
    for (int k = 0; k < PBLK2 / 8; ++k)
        m = fmaxf(m, partials2[(size_t)(i0 + k) * 128 + c]);
    red[t] = m;
    __syncthreads();
    if (t < 128) {
        float v = red[t];
#pragma unroll
        for (int s = 1; s < 8; ++s) v = fmaxf(v, red[s * 128 + t]);
        // bf16-round the pooled value (matches the prior pipeline numerics)
        red[t] = __uint_as_float((unsigned int)f2bf(v) << 16);
    }
    __syncthreads();
    if (t < 64) {
        int j = t & 7;
        int kk = t >> 3;
        float partial = 0.f;
        for (int k = kk * 16; k < kk * 16 + 16; ++k) partial += red[k] * Wfc[k * 8 + j];
        for (int o = 8; o < 64; o <<= 1) partial += __shfl_xor(partial, o);
        float logit = partial + bfc[j];
        float mxl = logit;
        for (int o = 1; o < 8; o <<= 1) mxl = fmaxf(mxl, __shfl_xor(mxl, o));
        float ex = __expf(logit - mxl);
        float sm = ex;
        for (int o = 1; o < 8; o <<= 1) sm += __shfl_xor(sm, o);
        if (t < 8) outp[t] = ex / sm;
    }
}

// ---------------- launch ----------------

extern "C" void kernel_launch(void* const* d_in, const int* in_sizes, int n_in,
                              void* d_out, int out_size, void* d_ws, size_t ws_size,
                              hipStream_t stream) {
    const float* x   = (const float*)d_in[0];
    const int*   src = (const int*)d_in[1];
    const int*   dst = (const int*)d_in[2];
    const float* W1  = (const float*)d_in[3];
    const float* al1 = (const float*)d_in[4];
    const float* ar1 = (const float*)d_in[5];
    const float* W2  = (const float*)d_in[6];
    const float* al2 = (const float*)d_in[7];
    const float* ar2 = (const float*)d_in[8];
    const float* W3  = (const float*)d_in[9];
    const float* al3 = (const float*)d_in[10];
    const float* ar3 = (const float*)d_in[11];
    const float* Wfc = (const float*)d_in[12];
    const float* bfc = (const float*)d_in[13];
    float* out = (float*)d_out;

    char* p = (char*)d_ws;
    auto alloc = [&](size_t bytes) {
        char* r = p;
        p += (bytes + 255) & ~(size_t)255;
        return r;
    };
    unsigned char* Fb_a = (unsigned char*)alloc((size_t)NN * FD);   // fp8 features
    unsigned char* Fb_b = (unsigned char*)alloc((size_t)NN * FD);
    unsigned int*  Hb   = (unsigned int*)alloc((size_t)NN * 64 * 4); // bf16x2-packed H
    float* el_a   = (float*)alloc((size_t)NN * 4 * 4);
    float* er_a   = (float*)alloc((size_t)NN * 4 * 4);
    int*   off    = (int*)alloc((size_t)NN * 4);
    int*   deg    = (int*)alloc((size_t)NN * 4);
    int*   ssrc   = (int*)alloc((size_t)NB * CAP * 4);
    unsigned int* pairs = (unsigned int*)alloc((size_t)NB * CAP * 4);
    int*   gcur   = (int*)alloc((size_t)NB * 4);
    float* partials  = (float*)alloc((size_t)AB * 128 * 4);     // 12.8 MB
    float* partials2 = (float*)alloc((size_t)PBLK2 * 128 * 4);  // 256 KB
    unsigned short* Wth = (unsigned short*)alloc(3 * 16384 * 2);
    // pairs (7.5 MB) is dead after k_sortgemm1's bsort -> overlay layer-B el/er (3.2 MB)
    float* el_b = (float*)pairs;
    float* er_b = (float*)pairs + (size_t)NN * 4;

    const int BB = (NE + CHUNK - 1) / CHUNK;  // 196

    k_wsplit<<<192, 256, 0, stream>>>(W1, W2, W3, Wth, gcur);
    k_bucket<<<BB, 256, 0, stream>>>(src, dst, gcur, pairs);

    // bsort + layer-1 GEMM fused (independent work) -> Fb_a (fp8), el_a, er_a
    k_sortgemm1<<<NB + GB, 256, 0, stream>>>(pairs, gcur, off, deg, ssrc,
                                             x, Wth, Fb_a, al1, ar1, el_a, er_a);
    // layer-1 agg -> Hb (bf16)
    k_agg8<<<AB, 256, 0, stream>>>(Fb_a, el_a, er_a, off, deg, ssrc, Hb);
    // layer-2 GEMM: Hb -> Fb_b (fp8), el_b, er_b
    k_gemm8<<<GB, 256, 0, stream>>>((const unsigned short*)Hb, Wth + 16384,
                                    Fb_b, al2, ar2, el_b, er_b);
    // layer-2 agg -> Hb
    k_agg8<<<AB, 256, 0, stream>>>(Fb_b, el_b, er_b, off, deg, ssrc, Hb);
    // layer-3 GEMM: Hb -> Fb_a (fp8), el_a, er_a
    k_gemm8<<<GB, 256, 0, stream>>>((const unsigned short*)Hb, Wth + 32768,
                                    Fb_a, al3, ar3, el_a, er_a);
    // layer-3 agg + block-local max pool
    k_aggpool8<<<AB, 256, 0, stream>>>(Fb_a, el_a, er_a, off, deg, ssrc, partials);
    k_poolred<<<PBLK2, 128, 0, stream>>>(partials, partials2);
    k_final<<<1, 1024, 0, stream>>>(partials2, Wfc, bfc, out);
}